// Round 2
// baseline (120.618 us; speedup 1.0000x reference)
//
#include <hip/hip_runtime.h>

typedef _Float16 half8 __attribute__((ext_vector_type(8)));
typedef float floatx4 __attribute__((ext_vector_type(4)));
typedef unsigned int uint2v __attribute__((ext_vector_type(2)));

#define NSPLIT 64
#define KS 64
#define DIM 2048
#define NROW 128          // 2*KS rows of T per split
#define BK 128            // k-panel width
#define NKC (DIM / BK)    // 16 panels
#define SST 152           // stage row stride (fp16 elems): 304 B, 16B-aligned, 2-way banks (free)
#define GST 129           // gram row stride (fp32 elems), conflict-free

// pack two f32 -> one u32 of fp16 pair (rtz)
__device__ __forceinline__ unsigned int pk16(float a, float b) {
  return __builtin_bit_cast(unsigned int, __builtin_amdgcn_cvt_pkrtz(a, b));
}

__global__ void init_out_kernel(float* out) {
  if (threadIdx.x < 6) out[threadIdx.x] = 0.0f;
}

__global__ __launch_bounds__(1024) void mmd_kernel(const float* __restrict__ src,
                                                   const float* __restrict__ tgt,
                                                   float* __restrict__ out) {
  __shared__ __align__(16) _Float16 stage[NROW * SST];  // ~38 KB
  __shared__ __align__(16) float gram[NROW * GST];      // ~64.5 KB
  __shared__ float sqv[NROW];
  __shared__ float reds[16];
  __shared__ float redm[16];
  __shared__ float quad[4];
  __shared__ float bcast[8];

  const int p = blockIdx.x;
  const int tid = threadIdx.x;
  const int lane = tid & 63;
  const int wave = tid >> 6;

  // ---- staging coords: thread t loads row srow, 4x float4 at cols c4 + {0,32,64,96}
  const int srow = tid >> 3;
  const int c4 = (tid & 7) * 4;
  const float* rowp = (srow < KS) ? (src + (size_t)(p * KS + srow) * DIM)
                                  : (tgt + (size_t)(p * KS + (srow - KS)) * DIM);

  // ---- mfma coords: 16 waves in 4x4 grid; wave computes 32x32 (2x2 tiles of 16x16)
  const int wr = (wave >> 2) * 32;
  const int wc = (wave & 3) * 32;
  const int fr = lane & 15;
  const int fk = (lane >> 4) * 8;

  floatx4 acc00 = {0.f, 0.f, 0.f, 0.f};
  floatx4 acc01 = {0.f, 0.f, 0.f, 0.f};
  floatx4 acc10 = {0.f, 0.f, 0.f, 0.f};
  floatx4 acc11 = {0.f, 0.f, 0.f, 0.f};

  float4 f0, f1, f2, f3;
#define LOADK(kc)                                      \
  do {                                                 \
    const float* gp_ = rowp + (kc) * BK + c4;          \
    f0 = *(const float4*)(gp_);                        \
    f1 = *(const float4*)(gp_ + 32);                   \
    f2 = *(const float4*)(gp_ + 64);                   \
    f3 = *(const float4*)(gp_ + 96);                   \
  } while (0)

  LOADK(0);
  for (int kc = 0; kc < NKC; ++kc) {
    __syncthreads();  // previous iteration's LDS reads done before overwrite
    {
      _Float16* sp = &stage[srow * SST + c4];
      *(uint2v*)(sp)      = (uint2v){pk16(f0.x, f0.y), pk16(f0.z, f0.w)};
      *(uint2v*)(sp + 32) = (uint2v){pk16(f1.x, f1.y), pk16(f1.z, f1.w)};
      *(uint2v*)(sp + 64) = (uint2v){pk16(f2.x, f2.y), pk16(f2.z, f2.w)};
      *(uint2v*)(sp + 96) = (uint2v){pk16(f3.x, f3.y), pk16(f3.z, f3.w)};
    }
    __syncthreads();
    if (kc + 1 < NKC) LOADK(kc + 1);  // prefetch hides under MFMA
#pragma unroll
    for (int ks = 0; ks < 4; ++ks) {
      const int ko = ks * 32 + fk;
      half8 a0 = *(const half8*)&stage[(wr + fr) * SST + ko];
      half8 a1 = *(const half8*)&stage[(wr + 16 + fr) * SST + ko];
      half8 b0 = *(const half8*)&stage[(wc + fr) * SST + ko];
      half8 b1 = *(const half8*)&stage[(wc + 16 + fr) * SST + ko];
      acc00 = __builtin_amdgcn_mfma_f32_16x16x32_f16(a0, b0, acc00, 0, 0, 0);
      acc01 = __builtin_amdgcn_mfma_f32_16x16x32_f16(a0, b1, acc01, 0, 0, 0);
      acc10 = __builtin_amdgcn_mfma_f32_16x16x32_f16(a1, b0, acc10, 0, 0, 0);
      acc11 = __builtin_amdgcn_mfma_f32_16x16x32_f16(a1, b1, acc11, 0, 0, 0);
    }
  }
#undef LOADK

  // ---- write gram to LDS. C/D layout: col = lane&15, row = (lane>>4)*4 + reg
  {
    const int ccol = lane & 15;
    const int crow = (lane >> 4) * 4;
#pragma unroll
    for (int r = 0; r < 4; ++r) {
      gram[(wr + crow + r) * GST + (wc + ccol)] = acc00[r];
      gram[(wr + crow + r) * GST + (wc + 16 + ccol)] = acc01[r];
      gram[(wr + 16 + crow + r) * GST + (wc + ccol)] = acc10[r];
      gram[(wr + 16 + crow + r) * GST + (wc + 16 + ccol)] = acc11[r];
    }
  }
  if (tid < 4) quad[tid] = 0.0f;
  __syncthreads();

  if (tid < NROW) sqv[tid] = gram[tid * GST + tid];  // sq from diagonal -> exact l2_ii = 0
  __syncthreads();

  // ---- l2 phase: 16 entries per thread (row = tid>>3, cols c0..c0+15), kept in regs
  const int row = tid >> 3;
  const int c0 = (tid & 7) * 16;
  float l2r[16];
  float lsum = 0.0f;
  float lmax = -1e30f;
  const float sqi = sqv[row];
#pragma unroll
  for (int m = 0; m < 16; ++m) {
    float g = gram[row * GST + c0 + m];
    float v = sqi + sqv[c0 + m] - 2.0f * g;
    l2r[m] = v;
    lsum += v;
    lmax = fmaxf(lmax, v);
  }
#pragma unroll
  for (int m = 1; m <= 32; m <<= 1) {
    lsum += __shfl_xor(lsum, m, 64);
    lmax = fmaxf(lmax, __shfl_xor(lmax, m, 64));
  }
  if (lane == 0) {
    reds[wave] = lsum;
    redm[wave] = lmax;
  }
  __syncthreads();
  if (tid == 0) {
    float tot = 0.0f, mx = -1e30f;
    for (int w = 0; w < 16; ++w) {
      tot += reds[w];
      mx = fmaxf(mx, redm[w]);
    }
    float bw = tot / (float)(NROW * NROW - NROW) * 0.25f;  // /(n^2-n) then /KERNEL_MUL^2
    float mult = 1.0f;
    for (int k = 0; k < 5; ++k) {
      bcast[k] = 1.0f / (bw * mult + 1e-9f);
      mult *= 2.0f;
    }
    if (p == NSPLIT - 1) out[1] = mx;  // max_l2 of last split
  }
  __syncthreads();

  const float ib0 = bcast[0], ib1 = bcast[1], ib2 = bcast[2], ib3 = bcast[3], ib4 = bcast[4];
  float qsum = 0.0f;
#pragma unroll
  for (int m = 0; m < 16; ++m) {
    float v = l2r[m];
    qsum += __expf(-v * ib0) + __expf(-v * ib1) + __expf(-v * ib2) +
            __expf(-v * ib3) + __expf(-v * ib4);
  }
  // combine the 32 lanes sharing the same (row-half, col-half); bit2 of lane = col-half
  qsum += __shfl_xor(qsum, 1, 64);
  qsum += __shfl_xor(qsum, 2, 64);
  qsum += __shfl_xor(qsum, 8, 64);
  qsum += __shfl_xor(qsum, 16, 64);
  qsum += __shfl_xor(qsum, 32, 64);
  if (lane == 0 || lane == 4) {
    int q = (wave >= 8 ? 2 : 0) + ((lane >> 2) & 1);  // q: 0=XX 1=XY 2=YX 3=YY
    atomicAdd(&quad[q], qsum);
  }
  __syncthreads();

  if (tid == 0) {
    const float inv = 1.0f / (4096.0f * 64.0f);  // mean over 64x64, then /P
    float xx = quad[0], xy = quad[1], yx = quad[2], yy = quad[3];
    atomicAdd(&out[0], (xx + yy - xy - yx) * inv);
    atomicAdd(&out[2], xx * inv);
    atomicAdd(&out[3], yy * inv);
    atomicAdd(&out[4], xy * inv);
    atomicAdd(&out[5], yx * inv);
  }
}

extern "C" void kernel_launch(void* const* d_in, const int* in_sizes, int n_in,
                              void* d_out, int out_size, void* d_ws, size_t ws_size,
                              hipStream_t stream) {
  const float* src = (const float*)d_in[0];
  const float* tgt = (const float*)d_in[1];
  float* out = (float*)d_out;
  init_out_kernel<<<1, 64, 0, stream>>>(out);
  mmd_kernel<<<NSPLIT, 1024, 0, stream>>>(src, tgt, out);
}

// Round 3
// 112.791 us; speedup vs baseline: 1.0694x; 1.0694x over previous
//
#include <hip/hip_runtime.h>

typedef _Float16 half8 __attribute__((ext_vector_type(8)));
typedef float floatx4 __attribute__((ext_vector_type(4)));
typedef unsigned int uint2v __attribute__((ext_vector_type(2)));

#define NSPLIT 64
#define KS 64
#define DIM 2048
#define NROW 128          // 2*KS rows of T per split
#define BK 128            // k-panel width
#define KSPL 4            // k-chunks per split (one block each)
#define KCH (DIM / KSPL)  // 512
#define NKC_A (KCH / BK)  // 4 panels per block
#define SST 152           // stage row stride (fp16 elems): 304 B, 16B-aligned, 2-way banks (free)
#define GSZ (NROW * NROW) // partial-gram slab elems (fp32)

// pack two f32 -> one u32 of fp16 pair (rtz)
__device__ __forceinline__ unsigned int pk16(float a, float b) {
  return __builtin_bit_cast(unsigned int, __builtin_amdgcn_cvt_pkrtz(a, b));
}

__global__ void init_out_kernel(float* out) {
  if (threadIdx.x < 6) out[threadIdx.x] = 0.0f;
}

// ---- Kernel A: partial gram over one k-chunk. grid = NSPLIT*KSPL = 256 blocks.
__global__ __launch_bounds__(1024) void gram_kernel(const float* __restrict__ src,
                                                    const float* __restrict__ tgt,
                                                    float* __restrict__ ws) {
  __shared__ __align__(16) _Float16 stage[NROW * SST];  // ~38 KB

  const int p = blockIdx.x >> 2;
  const int c = blockIdx.x & (KSPL - 1);
  const int tid = threadIdx.x;
  const int lane = tid & 63;
  const int wave = tid >> 6;

  // staging coords: thread loads row srow, 4x float4 at cols c4 + {0,32,64,96} within panel
  const int srow = tid >> 3;
  const int c4 = (tid & 7) * 4;
  const float* rowp = ((srow < KS) ? (src + (size_t)(p * KS + srow) * DIM)
                                   : (tgt + (size_t)(p * KS + (srow - KS)) * DIM)) +
                      c * KCH;

  // mfma coords: 16 waves in 4x4 grid; wave computes 32x32 (2x2 tiles of 16x16)
  const int wr = (wave >> 2) * 32;
  const int wc = (wave & 3) * 32;
  const int fr = lane & 15;
  const int fk = (lane >> 4) * 8;

  floatx4 acc00 = {0.f, 0.f, 0.f, 0.f};
  floatx4 acc01 = {0.f, 0.f, 0.f, 0.f};
  floatx4 acc10 = {0.f, 0.f, 0.f, 0.f};
  floatx4 acc11 = {0.f, 0.f, 0.f, 0.f};

  float4 f0, f1, f2, f3;
#define LOADK(kc)                                      \
  do {                                                 \
    const float* gp_ = rowp + (kc) * BK + c4;          \
    f0 = *(const float4*)(gp_);                        \
    f1 = *(const float4*)(gp_ + 32);                   \
    f2 = *(const float4*)(gp_ + 64);                   \
    f3 = *(const float4*)(gp_ + 96);                   \
  } while (0)

  LOADK(0);
  for (int kc = 0; kc < NKC_A; ++kc) {
    __syncthreads();  // previous iteration's LDS reads done before overwrite
    {
      _Float16* sp = &stage[srow * SST + c4];
      *(uint2v*)(sp)      = (uint2v){pk16(f0.x, f0.y), pk16(f0.z, f0.w)};
      *(uint2v*)(sp + 32) = (uint2v){pk16(f1.x, f1.y), pk16(f1.z, f1.w)};
      *(uint2v*)(sp + 64) = (uint2v){pk16(f2.x, f2.y), pk16(f2.z, f2.w)};
      *(uint2v*)(sp + 96) = (uint2v){pk16(f3.x, f3.y), pk16(f3.z, f3.w)};
    }
    __syncthreads();
    if (kc + 1 < NKC_A) LOADK(kc + 1);  // prefetch hides under MFMA
#pragma unroll
    for (int ks = 0; ks < 4; ++ks) {
      const int ko = ks * 32 + fk;
      half8 a0 = *(const half8*)&stage[(wr + fr) * SST + ko];
      half8 a1 = *(const half8*)&stage[(wr + 16 + fr) * SST + ko];
      half8 b0 = *(const half8*)&stage[(wc + fr) * SST + ko];
      half8 b1 = *(const half8*)&stage[(wc + 16 + fr) * SST + ko];
      acc00 = __builtin_amdgcn_mfma_f32_16x16x32_f16(a0, b0, acc00, 0, 0, 0);
      acc01 = __builtin_amdgcn_mfma_f32_16x16x32_f16(a0, b1, acc01, 0, 0, 0);
      acc10 = __builtin_amdgcn_mfma_f32_16x16x32_f16(a1, b0, acc10, 0, 0, 0);
      acc11 = __builtin_amdgcn_mfma_f32_16x16x32_f16(a1, b1, acc11, 0, 0, 0);
    }
  }
#undef LOADK

  // store partial gram slab. C/D layout: col = lane&15, row = (lane>>4)*4 + reg
  float* wsp = ws + (size_t)blockIdx.x * GSZ;
  const int ccol = lane & 15;
  const int crow = (lane >> 4) * 4;
#pragma unroll
  for (int r = 0; r < 4; ++r) {
    wsp[(wr + crow + r) * NROW + (wc + ccol)] = acc00[r];
    wsp[(wr + crow + r) * NROW + (wc + 16 + ccol)] = acc01[r];
    wsp[(wr + 16 + crow + r) * NROW + (wc + ccol)] = acc10[r];
    wsp[(wr + 16 + crow + r) * NROW + (wc + 16 + ccol)] = acc11[r];
  }
}

// ---- Kernel B: sum slabs, l2, bw, exp, quadrant means. grid = NSPLIT.
__global__ __launch_bounds__(1024) void reduce_kernel(const float* __restrict__ ws,
                                                      float* __restrict__ out) {
  __shared__ float sqv[NROW];
  __shared__ float reds[16];
  __shared__ float redm[16];
  __shared__ float quad[4];
  __shared__ float bcast[8];

  const int p = blockIdx.x;
  const int tid = threadIdx.x;
  const int lane = tid & 63;
  const int wave = tid >> 6;

  // thread owns gram entries (row, c0..c0+15)
  const int row = tid >> 3;
  const int c0 = (tid & 7) * 16;

  const float* base = ws + (size_t)p * KSPL * GSZ + row * NROW + c0;
  float4 g0 = {0.f, 0.f, 0.f, 0.f}, g1 = g0, g2 = g0, g3 = g0;
#pragma unroll
  for (int c = 0; c < KSPL; ++c) {
    const float* bp = base + (size_t)c * GSZ;
    float4 t0 = *(const float4*)(bp);
    float4 t1 = *(const float4*)(bp + 4);
    float4 t2 = *(const float4*)(bp + 8);
    float4 t3 = *(const float4*)(bp + 12);
    g0.x += t0.x; g0.y += t0.y; g0.z += t0.z; g0.w += t0.w;
    g1.x += t1.x; g1.y += t1.y; g1.z += t1.z; g1.w += t1.w;
    g2.x += t2.x; g2.y += t2.y; g2.z += t2.z; g2.w += t2.w;
    g3.x += t3.x; g3.y += t3.y; g3.z += t3.z; g3.w += t3.w;
  }
  float gs[16] = {g0.x, g0.y, g0.z, g0.w, g1.x, g1.y, g1.z, g1.w,
                  g2.x, g2.y, g2.z, g2.w, g3.x, g3.y, g3.z, g3.w};

  // share the diagonal (sq): diag entry (row,row) owned by thread with (tid&7)==row>>4
  if ((tid & 7) == (row >> 4)) sqv[row] = gs[row & 15];
  if (tid < 4) quad[tid] = 0.0f;
  __syncthreads();

  float l2r[16];
  float lsum = 0.0f;
  float lmax = -1e30f;
  const float sqi = sqv[row];
#pragma unroll
  for (int m = 0; m < 16; ++m) {
    float v = sqi + sqv[c0 + m] - 2.0f * gs[m];
    l2r[m] = v;
    lsum += v;
    lmax = fmaxf(lmax, v);
  }
#pragma unroll
  for (int m = 1; m <= 32; m <<= 1) {
    lsum += __shfl_xor(lsum, m, 64);
    lmax = fmaxf(lmax, __shfl_xor(lmax, m, 64));
  }
  if (lane == 0) {
    reds[wave] = lsum;
    redm[wave] = lmax;
  }
  __syncthreads();
  if (tid == 0) {
    float tot = 0.0f, mx = -1e30f;
    for (int w = 0; w < 16; ++w) {
      tot += reds[w];
      mx = fmaxf(mx, redm[w]);
    }
    float bw = tot / (float)(NROW * NROW - NROW) * 0.25f;  // /(n^2-n) then /KERNEL_MUL^2
    float mult = 1.0f;
    for (int k = 0; k < 5; ++k) {
      bcast[k] = 1.0f / (bw * mult + 1e-9f);
      mult *= 2.0f;
    }
    if (p == NSPLIT - 1) out[1] = mx;  // max_l2 of last split
  }
  __syncthreads();

  const float ib0 = bcast[0], ib1 = bcast[1], ib2 = bcast[2], ib3 = bcast[3], ib4 = bcast[4];
  float qsum = 0.0f;
#pragma unroll
  for (int m = 0; m < 16; ++m) {
    float v = l2r[m];
    qsum += __expf(-v * ib0) + __expf(-v * ib1) + __expf(-v * ib2) +
            __expf(-v * ib3) + __expf(-v * ib4);
  }
  // combine lanes: bits 0,1 (col chunk), 3,4,5 (row) — leaves bit2 = col-half
  qsum += __shfl_xor(qsum, 1, 64);
  qsum += __shfl_xor(qsum, 2, 64);
  qsum += __shfl_xor(qsum, 8, 64);
  qsum += __shfl_xor(qsum, 16, 64);
  qsum += __shfl_xor(qsum, 32, 64);
  if (lane == 0 || lane == 4) {
    int q = (wave >= 8 ? 2 : 0) + ((lane >> 2) & 1);  // 0=XX 1=XY 2=YX 3=YY
    atomicAdd(&quad[q], qsum);
  }
  __syncthreads();

  if (tid == 0) {
    const float inv = 1.0f / (4096.0f * 64.0f);  // mean over 64x64, then /P
    float xx = quad[0], xy = quad[1], yx = quad[2], yy = quad[3];
    atomicAdd(&out[0], (xx + yy - xy - yx) * inv);
    atomicAdd(&out[2], xx * inv);
    atomicAdd(&out[3], yy * inv);
    atomicAdd(&out[4], xy * inv);
    atomicAdd(&out[5], yx * inv);
  }
}

extern "C" void kernel_launch(void* const* d_in, const int* in_sizes, int n_in,
                              void* d_out, int out_size, void* d_ws, size_t ws_size,
                              hipStream_t stream) {
  const float* src = (const float*)d_in[0];
  const float* tgt = (const float*)d_in[1];
  float* out = (float*)d_out;
  float* ws = (float*)d_ws;  // needs NSPLIT*KSPL*128*128*4 = 16.8 MB
  init_out_kernel<<<1, 64, 0, stream>>>(out);
  gram_kernel<<<NSPLIT * KSPL, 1024, 0, stream>>>(src, tgt, ws);
  reduce_kernel<<<NSPLIT, 1024, 0, stream>>>(ws, out);
}